// Round 12
// baseline (106.618 us; speedup 1.0000x reference)
//
#include <hip/hip_runtime.h>

typedef unsigned short u16;
typedef __attribute__((ext_vector_type(8))) short bf16x8;
typedef __attribute__((ext_vector_type(4))) float f32x4;
typedef __attribute__((ext_vector_type(16))) float f32x16;
typedef __attribute__((ext_vector_type(4))) unsigned short u16x4;

// ---------- helpers ----------
__device__ __forceinline__ u16 f2bf(float f) {
    unsigned u = __float_as_uint(f);
    u = u + 0x7FFFu + ((u >> 16) & 1u);   // RTNE
    return (u16)(u >> 16);
}

__device__ __forceinline__ void gload16(const void* g, void* l) {
    __builtin_amdgcn_global_load_lds(
        (const __attribute__((address_space(1))) unsigned int*)g,
        (__attribute__((address_space(3))) unsigned int*)l,
        16, 0, 0);
}

__device__ __forceinline__ f32x4 mfma16(bf16x8 a, bf16x8 b, f32x4 c) {
    return __builtin_amdgcn_mfma_f32_16x16x32_bf16(a, b, c, 0, 0, 0);
}
__device__ __forceinline__ f32x16 mfma32(bf16x8 a, bf16x8 b, f32x16 c) {
    return __builtin_amdgcn_mfma_f32_32x32x16_bf16(a, b, c, 0, 0, 0);
}

// ---------- fused fp32 -> bf16 convert (x, Wqkv, Wo -> contiguous ws region) ----------
__global__ __launch_bounds__(256) void cvt_all(const float* __restrict__ x,
                                               const float* __restrict__ wqkv,
                                               const float* __restrict__ wo,
                                               u16* __restrict__ dst) {
    int i = blockIdx.x * 256 + threadIdx.x;   // 2097152 float4s total
    float4 v;
    if (i < 1048576)       v = ((const float4*)x)[i];
    else if (i < 1835008)  v = ((const float4*)wqkv)[i - 1048576];
    else                   v = ((const float4*)wo)[i - 1835008];
    u16x4 o = { f2bf(v.x), f2bf(v.y), f2bf(v.z), f2bf(v.w) };
    ((u16x4*)dst)[i] = o;
}

// ---------- 256x192 3-phase GEMM (one head per tile): C = A*B^T + bias, bf16 out.
// Grid 16x16 = 256 blocks (100% CU coverage). FIFO-derived counted vmcnt.
// Fused V^T extraction: region B2 of each tile IS head h's V columns.
__global__ __launch_bounds__(512) void gemm192(const u16* __restrict__ A,
                                               const u16* __restrict__ Bm,
                                               const float* __restrict__ bias,
                                               u16* __restrict__ Cp,
                                               u16* __restrict__ Vt,
                                               int M, int N, int K) {
    __shared__ __align__(16) char lds[114688];   // A 64KB + B 48KB
    const int tid = threadIdx.x, lane = tid & 63, wave = tid >> 6;
    const int wr = wave >> 2, wc = wave & 3;
    const int l15 = lane & 15, l4 = lane >> 4;

    const int nx = gridDim.x, nwg = nx * gridDim.y;
    const int id = blockIdx.y * nx + blockIdx.x;
    const int wg = (id & 7) * (nwg >> 3) + (id >> 3);
    const int m0 = (wg / nx) * 256, n0 = (wg % nx) * 192;

    // A staging sources: region q, round r; chunk c = r*512+tid; pre-swizzled K-chunk
    const u16* asrc[2][2];
#pragma unroll
    for (int q = 0; q < 2; ++q)
#pragma unroll
        for (int r = 0; r < 2; ++r) {
            int c = r * 512 + tid;
            int lr = c >> 3;
            int kc = (c & 7) ^ (lr & 7);
            asrc[q][r] = A + (size_t)(m0 + lr + (lr & 64) + q * 64) * K + kc * 8;
        }
    // B staging sources: region r3 (64 rows), 1 round
    const u16* bsrc[3];
    {
        int lr2 = tid >> 3;
        int kc = (tid & 7) ^ (lr2 & 7);
#pragma unroll
        for (int r3 = 0; r3 < 3; ++r3)
            bsrc[r3] = Bm + (size_t)(n0 + r3 * 64 + lr2) * K + kc * 8;
    }
    const int sd0 = wave * 1024;
    const int sd1 = 8192 + wave * 1024;

    const int roA = (wr * 64 + l15) * 128;
    const int roB = (wc * 16 + l15) * 128;
    int ch16[2];
#pragma unroll
    for (int kk = 0; kk < 2; ++kk) ch16[kk] = ((kk * 4 + l4) ^ (l15 & 7)) * 16;

    f32x4 zero = {0.f, 0.f, 0.f, 0.f};
    f32x4 acc[2][3][4];   // [mh][third][fm]
#pragma unroll
    for (int a = 0; a < 2; ++a)
#pragma unroll
        for (int b = 0; b < 3; ++b)
#pragma unroll
            for (int c = 0; c < 4; ++c) acc[a][b][c] = zero;

#define STG_A(q, tt) { char* rb = lds + (((tt) & 1) * 32768) + (q) * 16384;           \
        gload16(asrc[q][0] + (size_t)(tt) * 64, rb + sd0);                             \
        gload16(asrc[q][1] + (size_t)(tt) * 64, rb + sd1); }
#define STG_B(r3, tt) { char* rb = lds + 65536 + (((tt) & 1) * 24576) + (r3) * 8192;  \
        gload16(bsrc[r3] + (size_t)(tt) * 64, rb + wave * 1024); }
#define MFMA_G(MH, TH, AF) {                                                           \
        _Pragma("unroll")                                                              \
        for (int fm = 0; fm < 4; ++fm)                                                 \
            _Pragma("unroll")                                                          \
            for (int kk = 0; kk < 2; ++kk)                                             \
                acc[MH][TH][fm] = mfma16(AF[fm][kk], bfr[TH][kk], acc[MH][TH][fm]); }

    // prologue: stage tile 0 in FIFO order SA0,SB0,SB1,SA1,SB2; wait first 4
    STG_A(0, 0); STG_B(0, 0); STG_B(1, 0); STG_A(1, 0); STG_B(2, 0);
    asm volatile("s_waitcnt vmcnt(3)" ::: "memory");
    asm volatile("s_barrier" ::: "memory");

    bf16x8 af0[4][2], af1[4][2], bfr[3][2];
    const int nt = K >> 6;
    for (int t = 0; t < nt; ++t) {
        const char* Ab = lds + (t & 1) * 32768;
        const char* Bb = lds + 65536 + (t & 1) * 24576;
        // ---- phase 0: reads Aq0, B0, B1; MFMA (m0,B0)+(m0,B1); stages SA0,SB0,SB1
#pragma unroll
        for (int fm = 0; fm < 4; ++fm)
#pragma unroll
            for (int kk = 0; kk < 2; ++kk)
                af0[fm][kk] = *(const bf16x8*)(Ab + roA + fm * 2048 + ch16[kk]);
#pragma unroll
        for (int th = 0; th < 2; ++th)
#pragma unroll
            for (int kk = 0; kk < 2; ++kk)
                bfr[th][kk] = *(const bf16x8*)(Bb + th * 8192 + roB + ch16[kk]);
        if (t < nt - 1) { STG_A(0, t + 1); STG_B(0, t + 1); STG_B(1, t + 1); }
        asm volatile("s_barrier" ::: "memory");
        __builtin_amdgcn_s_setprio(1);
        MFMA_G(0, 0, af0); MFMA_G(0, 1, af0);
        __builtin_amdgcn_s_setprio(0);
        if (t < nt - 1) asm volatile("s_waitcnt vmcnt(4)" ::: "memory");
        else            asm volatile("s_waitcnt vmcnt(0)" ::: "memory");
        asm volatile("s_barrier" ::: "memory");
        // ---- phase 1: reads Aq1, B2; MFMA (m0,B2)+(m1,B0); stages SA1
#pragma unroll
        for (int fm = 0; fm < 4; ++fm)
#pragma unroll
            for (int kk = 0; kk < 2; ++kk)
                af1[fm][kk] = *(const bf16x8*)(Ab + 16384 + roA + fm * 2048 + ch16[kk]);
#pragma unroll
        for (int kk = 0; kk < 2; ++kk)
            bfr[2][kk] = *(const bf16x8*)(Bb + 2 * 8192 + roB + ch16[kk]);
        if (t < nt - 1) { STG_A(1, t + 1); }
        asm volatile("s_barrier" ::: "memory");
        __builtin_amdgcn_s_setprio(1);
        MFMA_G(0, 2, af0); MFMA_G(1, 0, af1);
        __builtin_amdgcn_s_setprio(0);
        asm volatile("s_barrier" ::: "memory");
        // ---- phase 2: no reads; MFMA (m1,B1)+(m1,B2); stages SB2; W
        if (t < nt - 1) { STG_B(2, t + 1); }
        asm volatile("s_barrier" ::: "memory");
        __builtin_amdgcn_s_setprio(1);
        MFMA_G(1, 1, af1); MFMA_G(1, 2, af1);
        __builtin_amdgcn_s_setprio(0);
        if (t < nt - 1) asm volatile("s_waitcnt vmcnt(3)" ::: "memory");
        asm volatile("s_barrier" ::: "memory");
    }
#undef STG_A
#undef STG_B
#undef MFMA_G

    // epilogue: bias + bf16 store
    float bv[3];
#pragma unroll
    for (int th = 0; th < 3; ++th) bv[th] = bias[n0 + th * 64 + wc * 16 + l15];
#pragma unroll
    for (int mh = 0; mh < 2; ++mh)
#pragma unroll
        for (int fm = 0; fm < 4; ++fm)
#pragma unroll
            for (int j = 0; j < 4; ++j) {
                size_t row = (size_t)(m0 + wr * 128 + mh * 64 + fm * 16 + l4 * 4 + j);
#pragma unroll
                for (int th = 0; th < 3; ++th) {
                    int col = n0 + th * 64 + wc * 16 + l15;
                    Cp[row * (size_t)N + col] = f2bf(acc[mh][th][fm][j] + bv[th]);
                }
            }

    // ---- fused V^T extraction: tile = head h = n0/192; V cols = third 2 ----
    const int b_ = m0 >> 11, s0_ = m0 & 2047;
    const int h = n0 / 192;
    const int vl = wc * 16 + l15;   // V-dim index 0..63
#pragma unroll
    for (int mh = 0; mh < 2; ++mh)
#pragma unroll
        for (int fm = 0; fm < 4; ++fm) {
            int r0 = wr * 128 + mh * 64 + fm * 16 + l4 * 4;
            u16x4 w = { f2bf(acc[mh][2][fm][0] + bv[2]),
                        f2bf(acc[mh][2][fm][1] + bv[2]),
                        f2bf(acc[mh][2][fm][2] + bv[2]),
                        f2bf(acc[mh][2][fm][3] + bv[2]) };
            *(u16x4*)(lds + vl * 520 + r0 * 2) = w;
        }
    __syncthreads();
    {
        size_t vt_base = ((size_t)(b_ * 16 + h) * 64) * 2048 + s0_;
        for (int c = tid; c < 4096; c += 512) {
            int vl2 = c >> 6, sl = c & 63;
            u16x4 w = *(const u16x4*)(lds + vl2 * 520 + sl * 8);
            *(u16x4*)(Vt + (size_t)vl2 * 2048 + vt_base + sl * 4) = w;
        }
    }
}

// ---------- 256x64 2-phase out-projection: C[M,N] = A*B^T + bias, f32 out.
__global__ __launch_bounds__(512) void gemm_out(const u16* __restrict__ A,
                                                const u16* __restrict__ Bm,
                                                const float* __restrict__ bias,
                                                float* __restrict__ Cp,
                                                int M, int N, int K) {
    __shared__ __align__(16) char lds[81920];   // A 64KB dbuf + B 16KB dbuf
    const int tid = threadIdx.x, lane = tid & 63, wave = tid >> 6;
    const int wr = wave >> 2, wc = wave & 3;
    const int l15 = lane & 15, l4 = lane >> 4;

    const int nx = gridDim.x, nwg = nx * gridDim.y;
    const int id = blockIdx.y * nx + blockIdx.x;
    const int wg = (id & 7) * (nwg >> 3) + (id >> 3);
    const int m0 = (wg / nx) * 256, n0 = (wg % nx) * 64;

    const u16* asrc[2][2];
#pragma unroll
    for (int q = 0; q < 2; ++q)
#pragma unroll
        for (int r = 0; r < 2; ++r) {
            int c = r * 512 + tid;
            int lr = c >> 3;
            int kc = (c & 7) ^ (lr & 7);
            asrc[q][r] = A + (size_t)(m0 + lr + (lr & 64) + q * 64) * K + kc * 8;
        }
    const u16* bsrc;
    {
        int lr2 = tid >> 3;
        int kc = (tid & 7) ^ (lr2 & 7);
        bsrc = Bm + (size_t)(n0 + lr2) * K + kc * 8;
    }
    const int sd0 = wave * 1024;
    const int sd1 = 8192 + wave * 1024;

    const int roA = (wr * 64 + l15) * 128;
    const int roB = (wc * 16 + l15) * 128;
    int ch16[2];
#pragma unroll
    for (int kk = 0; kk < 2; ++kk) ch16[kk] = ((kk * 4 + l4) ^ (l15 & 7)) * 16;

    f32x4 zero = {0.f, 0.f, 0.f, 0.f};
    f32x4 acc[2][4];   // [mh][fm]
#pragma unroll
    for (int a = 0; a < 2; ++a)
#pragma unroll
        for (int c = 0; c < 4; ++c) acc[a][c] = zero;

#define SGA(q, tt) { char* rb = lds + (((tt) & 1) * 32768) + (q) * 16384;   \
        gload16(asrc[q][0] + (size_t)(tt) * 64, rb + sd0);                   \
        gload16(asrc[q][1] + (size_t)(tt) * 64, rb + sd1); }
#define SGB(tt) { char* rb = lds + 65536 + (((tt) & 1) * 8192);              \
        gload16(bsrc + (size_t)(tt) * 64, rb + wave * 1024); }

    // prologue: FIFO order SA0,SA0,SB,SA1,SA1; drain first 3 for p0
    SGA(0, 0); SGB(0); SGA(1, 0);
    asm volatile("s_waitcnt vmcnt(2)" ::: "memory");
    asm volatile("s_barrier" ::: "memory");

    bf16x8 af0[4][2], af1[4][2], bfr[2];
    const int nt = K >> 6;
    for (int t = 0; t < nt; ++t) {
        const char* Ab = lds + (t & 1) * 32768;
        const char* Bb = lds + 65536 + (t & 1) * 8192;
        // ---- phase 0: reads Aq0 + B; MFMA mh0; stages SA0,SB
#pragma unroll
        for (int fm = 0; fm < 4; ++fm)
#pragma unroll
            for (int kk = 0; kk < 2; ++kk)
                af0[fm][kk] = *(const bf16x8*)(Ab + roA + fm * 2048 + ch16[kk]);
#pragma unroll
        for (int kk = 0; kk < 2; ++kk)
            bfr[kk] = *(const bf16x8*)(Bb + roB + ch16[kk]);
        if (t < nt - 1) { SGA(0, t + 1); SGB(t + 1); }
        asm volatile("s_barrier" ::: "memory");
        __builtin_amdgcn_s_setprio(1);
#pragma unroll
        for (int fm = 0; fm < 4; ++fm)
#pragma unroll
            for (int kk = 0; kk < 2; ++kk)
                acc[0][fm] = mfma16(af0[fm][kk], bfr[kk], acc[0][fm]);
        __builtin_amdgcn_s_setprio(0);
        if (t < nt - 1) asm volatile("s_waitcnt vmcnt(3)" ::: "memory");
        else            asm volatile("s_waitcnt vmcnt(0)" ::: "memory");
        asm volatile("s_barrier" ::: "memory");
        // ---- phase 1: reads Aq1 (B held in regs); MFMA mh1; stages SA1
#pragma unroll
        for (int fm = 0; fm < 4; ++fm)
#pragma unroll
            for (int kk = 0; kk < 2; ++kk)
                af1[fm][kk] = *(const bf16x8*)(Ab + 16384 + roA + fm * 2048 + ch16[kk]);
        if (t < nt - 1) { SGA(1, t + 1); }
        asm volatile("s_barrier" ::: "memory");
        __builtin_amdgcn_s_setprio(1);
#pragma unroll
        for (int fm = 0; fm < 4; ++fm)
#pragma unroll
            for (int kk = 0; kk < 2; ++kk)
                acc[1][fm] = mfma16(af1[fm][kk], bfr[kk], acc[1][fm]);
        __builtin_amdgcn_s_setprio(0);
        if (t < nt - 1) asm volatile("s_waitcnt vmcnt(2)" ::: "memory");
        asm volatile("s_barrier" ::: "memory");
    }
#undef SGA
#undef SGB

    // epilogue: bias + f32 store
    float bv = bias[n0 + wc * 16 + l15];
#pragma unroll
    for (int mh = 0; mh < 2; ++mh)
#pragma unroll
        for (int fm = 0; fm < 4; ++fm)
#pragma unroll
            for (int j = 0; j < 4; ++j) {
                size_t row = (size_t)(m0 + wr * 128 + mh * 64 + fm * 16 + l4 * 4 + j);
                int col = n0 + wc * 16 + l15;
                Cp[row * (size_t)N + col] = acc[mh][fm][j] + bv;
            }
}

// ---------- flash attention: 8 waves, KV-split x2, fixed-max softmax.
// LDS diet: K double-buffered (32 KB) + V SINGLE-buffered (16 KB) = 48 KB
// -> 3 blocks/CU (24 waves, +50% TLP vs 64 KB / 2 blocks).
// Schedule: [vmcnt(0); barrier] -> issue K(t+1) -> QK/softmax/PV -> barrier
// -> issue V(t+1) (Vbuf free only after all waves finish PV(t)).
// Row-sum via VALU tree; anti-phase tile rotation; transposed merge. ----------
__global__ __launch_bounds__(512, 4) void attn_kernel(const u16* __restrict__ qkv,
                                                      const u16* __restrict__ Vt,
                                                      u16* __restrict__ vals) {
    __shared__ __align__(16) char lds[49152];
    const int L = blockIdx.x;            // 512 blocks, 1-D
    const int ord = L >> 3;
    const int hb = (L & 7) * 4 + (ord >> 4);
    const int qt = ord & 15;
    const int h = hb & 15, b = hb >> 4;
    const int st8 = (ord & 1) << 3;      // anti-phase: odd blocks start at tile 8
    const int tid = threadIdx.x, lane = tid & 63, wave = tid >> 6;
    const int gtid = tid & 255, qsub = wave & 3, kvh = wave >> 2;
    const int l31 = lane & 31, hi = lane >> 5;
    const float S2E = 0.18033688f;   // 0.125 * log2(e)

    // Q B-fragments, pre-scaled by S2E (re-rounded to bf16)
    const u16* qbase = qkv + (size_t)(b * 2048 + qt * 128 + qsub * 32 + l31) * 3072 + h * 192;
    bf16x8 Qf[4];
#pragma unroll
    for (int ks = 0; ks < 4; ++ks) {
        bf16x8 q = *(const bf16x8*)(qbase + ks * 16 + hi * 8);
#pragma unroll
        for (int j = 0; j < 8; ++j) {
            float f = __uint_as_float(((unsigned)(u16)q[j]) << 16) * S2E;
            q[j] = (short)f2bf(f);
        }
        Qf[ks] = q;
    }

    // staging: chunk c = i*256 + gtid -> (fi=c>>6, dl=c&63); fragment-ordered source
    const u16* kpb[2];
    const u16* vpb[2];
    int dst[2];
#pragma unroll
    for (int i = 0; i < 2; ++i) {
        int c = i * 256 + gtid;
        int fi = c >> 6, dl = c & 63;
        int mm = fi >> 2, ks = fi & 3;
        int row = mm * 32 + (dl & 31);
        int col = ks * 16 + (dl >> 5) * 8;
        kpb[i] = qkv + (size_t)(b * 2048 + kvh * 1024 + row) * 3072 + h * 192 + 64 + col;
        vpb[i] = Vt + ((size_t)((b * 16 + h) * 64 + row)) * 2048 + kvh * 1024 + col;
        dst[i] = fi * 512;
    }
    u16* Kst = (u16*)lds + kvh * 8192;            // K: 2 bufs x 4096 u16 per kvh [0,32768)B
    u16* Vst = (u16*)lds + 16384 + kvh * 4096;    // V: 1 buf  x 4096 u16 per kvh [32768,49152)B

    f32x16 accO[2];
#pragma unroll
    for (int md = 0; md < 2; ++md)
#pragma unroll
        for (int r = 0; r < 16; ++r) accO[md][r] = 0.f;
    float accLs = 0.f;

    const char* KsL = (const char*)Kst + lane * 16;
    const char* VsL = (const char*)Vst + lane * 16;

    // prologue: stage K(st8) -> Kbuf0, V(st8) -> Vbuf
#pragma unroll
    for (int i = 0; i < 2; ++i) gload16(kpb[i] + (size_t)st8 * 196608, Kst + dst[i]);
#pragma unroll
    for (int i = 0; i < 2; ++i) gload16(vpb[i] + (size_t)st8 * 64, Vst + dst[i]);

    for (int t = 0; t < 16; ++t) {
        // drain own stage loads (K(t) issued a tile early, V(t) issued at the
        // bottom of t-1); barrier: all of tile t's K/V resident, all waves past
        // t-1's reads -> safe to overwrite Kbuf[(t+1)&1] below.
        asm volatile("s_waitcnt vmcnt(0)" ::: "memory");
        asm volatile("s_barrier" ::: "memory");

        if (t < 15) {
            int phys = (t + 1 + st8) & 15;
            u16* kd = Kst + ((t + 1) & 1) * 4096;
#pragma unroll
            for (int i = 0; i < 2; ++i) gload16(kpb[i] + (size_t)phys * 196608, kd + dst[i]);
        }

        const char* Kb = KsL + (t & 1) * 8192;
        const char* Vb = VsL;

        // ---- QK^T (S^T): sc[m] rows = sk, cols = q (lane&31)
        f32x16 sc[2];
        __builtin_amdgcn_s_setprio(1);
#pragma unroll
        for (int m = 0; m < 2; ++m) {
            f32x16 c;
#pragma unroll
            for (int r = 0; r < 16; ++r) c[r] = 0.f;
#pragma unroll
            for (int ks = 0; ks < 4; ++ks) {
                bf16x8 kf = *(const bf16x8*)(Kb + (m * 4 + ks) * 1024);
                c = mfma32(kf, Qf[ks], c);
            }
            sc[m] = c;
        }
        __builtin_amdgcn_s_setprio(0);

        bf16x8 Pf[4];
#pragma unroll
        for (int r = 0; r < 16; ++r)
            sc[0][r] = __builtin_amdgcn_exp2f(sc[0][r]);
        {
            float q0 = (sc[0][0] + sc[0][1]) + (sc[0][2] + sc[0][3]);
            float q1 = (sc[0][4] + sc[0][5]) + (sc[0][6] + sc[0][7]);
            float q2 = (sc[0][8] + sc[0][9]) + (sc[0][10] + sc[0][11]);
            float q3 = (sc[0][12] + sc[0][13]) + (sc[0][14] + sc[0][15]);
            accLs += (q0 + q1) + (q2 + q3);
        }
        {
            unsigned W0[4], W1[4];
#pragma unroll
            for (int g = 0; g < 4; ++g) {
                asm("v_cvt_pk_bf16_f32 %0, %1, %2"
                    : "=v"(W0[g]) : "v"(sc[0][4 * g + 0]), "v"(sc[0][4 * g + 1]));
                asm("v_cvt_pk_bf16_f32 %0, %1, %2"
                    : "=v"(W1[g]) : "v"(sc[0][4 * g + 2]), "v"(sc[0][4 * g + 3]));
            }
#pragma unroll
            for (int kpair = 0; kpair < 2; ++kpair) {
                unsigned xa = W0[2 * kpair], ya = W0[2 * kpair + 1];
                unsigned xb = W1[2 * kpair], yb = W1[2 * kpair + 1];
                asm volatile("v_permlane32_swap_b32 %0, %1" : "+v"(xa), "+v"(ya));
                asm volatile("v_permlane32_swap_b32 %0, %1" : "+v"(xb), "+v"(yb));
                union { unsigned w[4]; bf16x8 v; } u;
                u.w[0] = xa; u.w[1] = xb; u.w[2] = ya; u.w[3] = yb;
                Pf[kpair] = u.v;
            }
        }

        // ---- PV half A (ks=0,1)
        __builtin_amdgcn_s_setprio(1);
#pragma unroll
        for (int md = 0; md < 2; ++md) {
            f32x16 c = accO[md];
#pragma unroll
            for (int ks = 0; ks < 2; ++ks) {
                bf16x8 vf = *(const bf16x8*)(Vb + (md * 4 + ks) * 1024);
                c = mfma32(vf, Pf[ks], c);
            }
            accO[md] = c;
        }
        __builtin_amdgcn_s_setprio(0);

#pragma unroll
        for (int r = 0; r < 16; ++r)
            sc[1][r] = __builtin_amdgcn_exp2f(sc[1][r]);
        {
            float q0 = (sc[1][0] + sc[1][1]) + (sc[1][2] + sc[1][3]);
            float q1 = (sc[1][4] + sc[1][5]) + (sc[1][6] + sc[1][7]);
            float q2 = (sc[1][8] + sc[1][9]) + (sc[1][10] + sc[1][11]);
            float q3 = (sc[1][12] + sc[1][13]) + (sc[1][14] + sc[1][15]);
            accLs += (q0 + q1) + (q2 + q3);
        }
        {
            unsigned W0[4], W1[4];
#pragma unroll
            for (int g = 0; g < 4; ++g) {
                asm("v_cvt_pk_bf16_f32 %0, %1, %2"
                    : "=v"(W0[g]) : "v"(sc[1][4 * g + 0]), "v"(sc[1][4 * g + 1]));
                asm("v_cvt_pk_bf16_f32 %0, %1, %2"
                    : "=v"(W1[g]) : "v"(sc[1][4 * g + 2]), "v"(sc[1][4 * g + 3]));
            }
#pragma unroll
            for (int kpair = 0; kpair < 2; ++kpair) {
                unsigned xa = W0[2 * kpair], ya = W0[2 * kpair + 1];
                unsigned xb = W1[2 * kpair], yb = W1[2 * kpair + 1];
                asm volatile("v_permlane32_swap_b32 %0, %1" : "+v"(xa), "+v"(ya));
                asm volatile("v_permlane32_swap_b32 %0, %1" : "+v"(xb), "+v"(yb));
                union { unsigned w[4]; bf16x8 v; } u;
                u.w[0] = xa; u.w[1] = xb; u.w[2] = ya; u.w[3] = yb;
                Pf[2 + kpair] = u.v;
            }
        }

        // ---- PV half B (ks=2,3)
        __builtin_amdgcn_s_setprio(1);
#pragma unroll
        for (int md = 0; md < 2; ++md) {
            f32x16 c = accO[md];
#pragma unroll
            for (int ks = 2; ks < 4; ++ks) {
                bf16x8 vf = *(const bf16x8*)(Vb + (md * 4 + ks) * 1024);
                c = mfma32(vf, Pf[ks], c);
            }
            accO[md] = c;
        }
        __builtin_amdgcn_s_setprio(0);

        // all waves done reading Vbuf for tile t -> safe to refill it
        asm volatile("s_barrier" ::: "memory");
        if (t < 15) {
            int phys = (t + 1 + st8) & 15;
#pragma unroll
            for (int i = 0; i < 2; ++i) gload16(vpb[i] + (size_t)phys * 64, Vst + dst[i]);
        }
    }

    float lt;
    {
        float xa = accLs, xb = accLs;
        asm volatile("v_permlane32_swap_b32 %0, %1" : "+v"(xa), "+v"(xb));
        lt = xa + xb;
    }

    // ---- merge the two KV halves via LDS (transposed, conflict-free)
    float* MO = (float*)lds;                 // 32 KB
    float* ML = (float*)(lds + 32768);       // 1 KB (V region dead by now)
    __syncthreads();
    if (kvh == 1) {
        int r = qsub * 64 + lane;
#pragma unroll
        for (int md = 0; md < 2; ++md)
#pragma unroll
            for (int g = 0; g < 4; ++g)
#pragma unroll
                for (int j = 0; j < 4; ++j)
                    MO[(md * 16 + 4 * g + j) * 256 + r] = accO[md][4 * g + j];
        ML[r] = lt;
    }
    __syncthreads();
    if (kvh == 0) {
        int r = qsub * 64 + lane;
        float inv = 1.f / (lt + ML[r]);
        size_t rowoff = (size_t)(b * 2048 + qt * 128 + qsub * 32 + l31) * 1024 + h * 64;
#pragma unroll
        for (int md = 0; md < 2; ++md)
#pragma unroll
            for (int g = 0; g < 4; ++g) {
                float w0 = MO[(md * 16 + 4 * g + 0) * 256 + r];
                float w1 = MO[(md * 16 + 4 * g + 1) * 256 + r];
                float w2 = MO[(md * 16 + 4 * g + 2) * 256 + r];
                float w3 = MO[(md * 16 + 4 * g + 3) * 256 + r];
                u16x4 o = { f2bf((accO[md][4 * g + 0] + w0) * inv),
                            f2bf((accO[md][4 * g + 1] + w1) * inv),
                            f2bf((accO[md][4 * g + 2] + w2) * inv),
                            f2bf((accO[md][4 * g + 3] + w3) * inv) };
                *(u16x4*)(vals + rowoff + md * 32 + 8 * g + 4 * hi) = o;
            }
    }
}

// ---------- launch ----------
extern "C" void kernel_launch(void* const* d_in, const int* in_sizes, int n_in,
                              void* d_out, int out_size, void* d_ws, size_t ws_size,
                              hipStream_t stream) {
    const float* x    = (const float*)d_in[0];
    const float* Wqkv = (const float*)d_in[1];
    const float* bqkv = (const float*)d_in[2];
    const float* Wo   = (const float*)d_in[3];
    const float* bo   = (const float*)d_in[4];
    float* out = (float*)d_out;

    char* ws = (char*)d_ws;
    u16* x_bf    = (u16*)(ws);                   // 8,388,608 B
    u16* Wqkv_bf = (u16*)(ws + 8388608);         // 6,291,456 B (contiguous with x_bf)
    u16* Wo_bf   = (u16*)(ws + 14680064);        // 2,097,152 B (contiguous)
    u16* qkv_bf  = (u16*)(ws + 16777216);
    u16* Vt      = (u16*)(ws + 41943040);
    u16* vals    = (u16*)(ws + 50331648);

    cvt_all<<<8192, 256, 0, stream>>>(x, Wqkv, Wo, x_bf);

    // qkv = x @ Wqkv^T + bqkv  (+ fused V^T extraction)  (M=4096, N=3072, K=1024)
    gemm192<<<dim3(16, 16), 512, 0, stream>>>(x_bf, Wqkv_bf, bqkv, qkv_bf, Vt,
                                              4096, 3072, 1024);

    attn_kernel<<<512, 512, 0, stream>>>(qkv_bf, Vt, vals);

    // out = vals @ Wo^T + bo  (M=4096, N=1024, K=1024), 256x64 tile, grid 256
    gemm_out<<<dim3(16, 16), 512, 0, stream>>>(vals, Wo_bf, bo, out,
                                               4096, 1024, 1024);
}

// Round 14
// 104.996 us; speedup vs baseline: 1.0154x; 1.0154x over previous
//
#include <hip/hip_runtime.h>

typedef unsigned short u16;
typedef __attribute__((ext_vector_type(8))) short bf16x8;
typedef __attribute__((ext_vector_type(4))) float f32x4;
typedef __attribute__((ext_vector_type(16))) float f32x16;
typedef __attribute__((ext_vector_type(4))) unsigned short u16x4;

// ---------- helpers ----------
__device__ __forceinline__ u16 f2bf(float f) {
    unsigned u = __float_as_uint(f);
    u = u + 0x7FFFu + ((u >> 16) & 1u);   // RTNE
    return (u16)(u >> 16);
}

__device__ __forceinline__ void gload16(const void* g, void* l) {
    __builtin_amdgcn_global_load_lds(
        (const __attribute__((address_space(1))) unsigned int*)g,
        (__attribute__((address_space(3))) unsigned int*)l,
        16, 0, 0);
}

__device__ __forceinline__ f32x4 mfma16(bf16x8 a, bf16x8 b, f32x4 c) {
    return __builtin_amdgcn_mfma_f32_16x16x32_bf16(a, b, c, 0, 0, 0);
}
__device__ __forceinline__ f32x16 mfma32(bf16x8 a, bf16x8 b, f32x16 c) {
    return __builtin_amdgcn_mfma_f32_32x32x16_bf16(a, b, c, 0, 0, 0);
}

// ---------- fused fp32 -> bf16 convert (x, Wqkv, Wo -> contiguous ws region) ----------
__global__ __launch_bounds__(256) void cvt_all(const float* __restrict__ x,
                                               const float* __restrict__ wqkv,
                                               const float* __restrict__ wo,
                                               u16* __restrict__ dst) {
    int i = blockIdx.x * 256 + threadIdx.x;   // 2097152 float4s total
    float4 v;
    if (i < 1048576)       v = ((const float4*)x)[i];
    else if (i < 1835008)  v = ((const float4*)wqkv)[i - 1048576];
    else                   v = ((const float4*)wo)[i - 1835008];
    u16x4 o = { f2bf(v.x), f2bf(v.y), f2bf(v.z), f2bf(v.w) };
    ((u16x4*)dst)[i] = o;
}

// ---------- 256x192 3-phase GEMM (one head per tile): C = A*B^T + bias, bf16 out.
// Grid 16x16 = 256 blocks (100% CU coverage). FIFO-derived counted vmcnt.
// Fused V^T extraction: region B2 of each tile IS head h's V columns.
__global__ __launch_bounds__(512) void gemm192(const u16* __restrict__ A,
                                               const u16* __restrict__ Bm,
                                               const float* __restrict__ bias,
                                               u16* __restrict__ Cp,
                                               u16* __restrict__ Vt,
                                               int M, int N, int K) {
    __shared__ __align__(16) char lds[114688];   // A 64KB + B 48KB
    const int tid = threadIdx.x, lane = tid & 63, wave = tid >> 6;
    const int wr = wave >> 2, wc = wave & 3;
    const int l15 = lane & 15, l4 = lane >> 4;

    const int nx = gridDim.x, nwg = nx * gridDim.y;
    const int id = blockIdx.y * nx + blockIdx.x;
    const int wg = (id & 7) * (nwg >> 3) + (id >> 3);
    const int m0 = (wg / nx) * 256, n0 = (wg % nx) * 192;

    // A staging sources: region q, round r; chunk c = r*512+tid; pre-swizzled K-chunk
    const u16* asrc[2][2];
#pragma unroll
    for (int q = 0; q < 2; ++q)
#pragma unroll
        for (int r = 0; r < 2; ++r) {
            int c = r * 512 + tid;
            int lr = c >> 3;
            int kc = (c & 7) ^ (lr & 7);
            asrc[q][r] = A + (size_t)(m0 + lr + (lr & 64) + q * 64) * K + kc * 8;
        }
    // B staging sources: region r3 (64 rows), 1 round
    const u16* bsrc[3];
    {
        int lr2 = tid >> 3;
        int kc = (tid & 7) ^ (lr2 & 7);
#pragma unroll
        for (int r3 = 0; r3 < 3; ++r3)
            bsrc[r3] = Bm + (size_t)(n0 + r3 * 64 + lr2) * K + kc * 8;
    }
    const int sd0 = wave * 1024;
    const int sd1 = 8192 + wave * 1024;

    const int roA = (wr * 64 + l15) * 128;
    const int roB = (wc * 16 + l15) * 128;
    int ch16[2];
#pragma unroll
    for (int kk = 0; kk < 2; ++kk) ch16[kk] = ((kk * 4 + l4) ^ (l15 & 7)) * 16;

    f32x4 zero = {0.f, 0.f, 0.f, 0.f};
    f32x4 acc[2][3][4];   // [mh][third][fm]
#pragma unroll
    for (int a = 0; a < 2; ++a)
#pragma unroll
        for (int b = 0; b < 3; ++b)
#pragma unroll
            for (int c = 0; c < 4; ++c) acc[a][b][c] = zero;

#define STG_A(q, tt) { char* rb = lds + (((tt) & 1) * 32768) + (q) * 16384;           \
        gload16(asrc[q][0] + (size_t)(tt) * 64, rb + sd0);                             \
        gload16(asrc[q][1] + (size_t)(tt) * 64, rb + sd1); }
#define STG_B(r3, tt) { char* rb = lds + 65536 + (((tt) & 1) * 24576) + (r3) * 8192;  \
        gload16(bsrc[r3] + (size_t)(tt) * 64, rb + wave * 1024); }
#define MFMA_G(MH, TH, AF) {                                                           \
        _Pragma("unroll")                                                              \
        for (int fm = 0; fm < 4; ++fm)                                                 \
            _Pragma("unroll")                                                          \
            for (int kk = 0; kk < 2; ++kk)                                             \
                acc[MH][TH][fm] = mfma16(AF[fm][kk], bfr[TH][kk], acc[MH][TH][fm]); }

    // prologue: stage tile 0 in FIFO order SA0,SB0,SB1,SA1,SB2; wait first 4
    STG_A(0, 0); STG_B(0, 0); STG_B(1, 0); STG_A(1, 0); STG_B(2, 0);
    asm volatile("s_waitcnt vmcnt(3)" ::: "memory");
    asm volatile("s_barrier" ::: "memory");

    bf16x8 af0[4][2], af1[4][2], bfr[3][2];
    const int nt = K >> 6;
    for (int t = 0; t < nt; ++t) {
        const char* Ab = lds + (t & 1) * 32768;
        const char* Bb = lds + 65536 + (t & 1) * 24576;
        // ---- phase 0: reads Aq0, B0, B1; MFMA (m0,B0)+(m0,B1); stages SA0,SB0,SB1
#pragma unroll
        for (int fm = 0; fm < 4; ++fm)
#pragma unroll
            for (int kk = 0; kk < 2; ++kk)
                af0[fm][kk] = *(const bf16x8*)(Ab + roA + fm * 2048 + ch16[kk]);
#pragma unroll
        for (int th = 0; th < 2; ++th)
#pragma unroll
            for (int kk = 0; kk < 2; ++kk)
                bfr[th][kk] = *(const bf16x8*)(Bb + th * 8192 + roB + ch16[kk]);
        if (t < nt - 1) { STG_A(0, t + 1); STG_B(0, t + 1); STG_B(1, t + 1); }
        asm volatile("s_barrier" ::: "memory");
        __builtin_amdgcn_s_setprio(1);
        MFMA_G(0, 0, af0); MFMA_G(0, 1, af0);
        __builtin_amdgcn_s_setprio(0);
        if (t < nt - 1) asm volatile("s_waitcnt vmcnt(4)" ::: "memory");
        else            asm volatile("s_waitcnt vmcnt(0)" ::: "memory");
        asm volatile("s_barrier" ::: "memory");
        // ---- phase 1: reads Aq1, B2; MFMA (m0,B2)+(m1,B0); stages SA1
#pragma unroll
        for (int fm = 0; fm < 4; ++fm)
#pragma unroll
            for (int kk = 0; kk < 2; ++kk)
                af1[fm][kk] = *(const bf16x8*)(Ab + 16384 + roA + fm * 2048 + ch16[kk]);
#pragma unroll
        for (int kk = 0; kk < 2; ++kk)
            bfr[2][kk] = *(const bf16x8*)(Bb + 2 * 8192 + roB + ch16[kk]);
        if (t < nt - 1) { STG_A(1, t + 1); }
        asm volatile("s_barrier" ::: "memory");
        __builtin_amdgcn_s_setprio(1);
        MFMA_G(0, 2, af0); MFMA_G(1, 0, af1);
        __builtin_amdgcn_s_setprio(0);
        asm volatile("s_barrier" ::: "memory");
        // ---- phase 2: no reads; MFMA (m1,B1)+(m1,B2); stages SB2; W
        if (t < nt - 1) { STG_B(2, t + 1); }
        asm volatile("s_barrier" ::: "memory");
        __builtin_amdgcn_s_setprio(1);
        MFMA_G(1, 1, af1); MFMA_G(1, 2, af1);
        __builtin_amdgcn_s_setprio(0);
        if (t < nt - 1) asm volatile("s_waitcnt vmcnt(3)" ::: "memory");
        asm volatile("s_barrier" ::: "memory");
    }
#undef STG_A
#undef STG_B
#undef MFMA_G

    // epilogue: bias + bf16 store
    float bv[3];
#pragma unroll
    for (int th = 0; th < 3; ++th) bv[th] = bias[n0 + th * 64 + wc * 16 + l15];
#pragma unroll
    for (int mh = 0; mh < 2; ++mh)
#pragma unroll
        for (int fm = 0; fm < 4; ++fm)
#pragma unroll
            for (int j = 0; j < 4; ++j) {
                size_t row = (size_t)(m0 + wr * 128 + mh * 64 + fm * 16 + l4 * 4 + j);
#pragma unroll
                for (int th = 0; th < 3; ++th) {
                    int col = n0 + th * 64 + wc * 16 + l15;
                    Cp[row * (size_t)N + col] = f2bf(acc[mh][th][fm][j] + bv[th]);
                }
            }

    // ---- fused V^T extraction: tile = head h = n0/192; V cols = third 2 ----
    const int b_ = m0 >> 11, s0_ = m0 & 2047;
    const int h = n0 / 192;
    const int vl = wc * 16 + l15;   // V-dim index 0..63
#pragma unroll
    for (int mh = 0; mh < 2; ++mh)
#pragma unroll
        for (int fm = 0; fm < 4; ++fm) {
            int r0 = wr * 128 + mh * 64 + fm * 16 + l4 * 4;
            u16x4 w = { f2bf(acc[mh][2][fm][0] + bv[2]),
                        f2bf(acc[mh][2][fm][1] + bv[2]),
                        f2bf(acc[mh][2][fm][2] + bv[2]),
                        f2bf(acc[mh][2][fm][3] + bv[2]) };
            *(u16x4*)(lds + vl * 520 + r0 * 2) = w;
        }
    __syncthreads();
    {
        size_t vt_base = ((size_t)(b_ * 16 + h) * 64) * 2048 + s0_;
        for (int c = tid; c < 4096; c += 512) {
            int vl2 = c >> 6, sl = c & 63;
            u16x4 w = *(const u16x4*)(lds + vl2 * 520 + sl * 8);
            *(u16x4*)(Vt + (size_t)vl2 * 2048 + vt_base + sl * 4) = w;
        }
    }
}

// ---------- 256x64 2-phase out-projection: C[M,N] = A*B^T + bias, f32 out.
__global__ __launch_bounds__(512) void gemm_out(const u16* __restrict__ A,
                                                const u16* __restrict__ Bm,
                                                const float* __restrict__ bias,
                                                float* __restrict__ Cp,
                                                int M, int N, int K) {
    __shared__ __align__(16) char lds[81920];   // A 64KB dbuf + B 16KB dbuf
    const int tid = threadIdx.x, lane = tid & 63, wave = tid >> 6;
    const int wr = wave >> 2, wc = wave & 3;
    const int l15 = lane & 15, l4 = lane >> 4;

    const int nx = gridDim.x, nwg = nx * gridDim.y;
    const int id = blockIdx.y * nx + blockIdx.x;
    const int wg = (id & 7) * (nwg >> 3) + (id >> 3);
    const int m0 = (wg / nx) * 256, n0 = (wg % nx) * 64;

    const u16* asrc[2][2];
#pragma unroll
    for (int q = 0; q < 2; ++q)
#pragma unroll
        for (int r = 0; r < 2; ++r) {
            int c = r * 512 + tid;
            int lr = c >> 3;
            int kc = (c & 7) ^ (lr & 7);
            asrc[q][r] = A + (size_t)(m0 + lr + (lr & 64) + q * 64) * K + kc * 8;
        }
    const u16* bsrc;
    {
        int lr2 = tid >> 3;
        int kc = (tid & 7) ^ (lr2 & 7);
        bsrc = Bm + (size_t)(n0 + lr2) * K + kc * 8;
    }
    const int sd0 = wave * 1024;
    const int sd1 = 8192 + wave * 1024;

    const int roA = (wr * 64 + l15) * 128;
    const int roB = (wc * 16 + l15) * 128;
    int ch16[2];
#pragma unroll
    for (int kk = 0; kk < 2; ++kk) ch16[kk] = ((kk * 4 + l4) ^ (l15 & 7)) * 16;

    f32x4 zero = {0.f, 0.f, 0.f, 0.f};
    f32x4 acc[2][4];   // [mh][fm]
#pragma unroll
    for (int a = 0; a < 2; ++a)
#pragma unroll
        for (int c = 0; c < 4; ++c) acc[a][c] = zero;

#define SGA(q, tt) { char* rb = lds + (((tt) & 1) * 32768) + (q) * 16384;   \
        gload16(asrc[q][0] + (size_t)(tt) * 64, rb + sd0);                   \
        gload16(asrc[q][1] + (size_t)(tt) * 64, rb + sd1); }
#define SGB(tt) { char* rb = lds + 65536 + (((tt) & 1) * 8192);              \
        gload16(bsrc + (size_t)(tt) * 64, rb + wave * 1024); }

    // prologue: FIFO order SA0,SA0,SB,SA1,SA1; drain first 3 for p0
    SGA(0, 0); SGB(0); SGA(1, 0);
    asm volatile("s_waitcnt vmcnt(2)" ::: "memory");
    asm volatile("s_barrier" ::: "memory");

    bf16x8 af0[4][2], af1[4][2], bfr[2];
    const int nt = K >> 6;
    for (int t = 0; t < nt; ++t) {
        const char* Ab = lds + (t & 1) * 32768;
        const char* Bb = lds + 65536 + (t & 1) * 8192;
        // ---- phase 0: reads Aq0 + B; MFMA mh0; stages SA0,SB
#pragma unroll
        for (int fm = 0; fm < 4; ++fm)
#pragma unroll
            for (int kk = 0; kk < 2; ++kk)
                af0[fm][kk] = *(const bf16x8*)(Ab + roA + fm * 2048 + ch16[kk]);
#pragma unroll
        for (int kk = 0; kk < 2; ++kk)
            bfr[kk] = *(const bf16x8*)(Bb + roB + ch16[kk]);
        if (t < nt - 1) { SGA(0, t + 1); SGB(t + 1); }
        asm volatile("s_barrier" ::: "memory");
        __builtin_amdgcn_s_setprio(1);
#pragma unroll
        for (int fm = 0; fm < 4; ++fm)
#pragma unroll
            for (int kk = 0; kk < 2; ++kk)
                acc[0][fm] = mfma16(af0[fm][kk], bfr[kk], acc[0][fm]);
        __builtin_amdgcn_s_setprio(0);
        if (t < nt - 1) asm volatile("s_waitcnt vmcnt(3)" ::: "memory");
        else            asm volatile("s_waitcnt vmcnt(0)" ::: "memory");
        asm volatile("s_barrier" ::: "memory");
        // ---- phase 1: reads Aq1 (B held in regs); MFMA mh1; stages SA1
#pragma unroll
        for (int fm = 0; fm < 4; ++fm)
#pragma unroll
            for (int kk = 0; kk < 2; ++kk)
                af1[fm][kk] = *(const bf16x8*)(Ab + 16384 + roA + fm * 2048 + ch16[kk]);
        if (t < nt - 1) { SGA(1, t + 1); }
        asm volatile("s_barrier" ::: "memory");
        __builtin_amdgcn_s_setprio(1);
#pragma unroll
        for (int fm = 0; fm < 4; ++fm)
#pragma unroll
            for (int kk = 0; kk < 2; ++kk)
                acc[1][fm] = mfma16(af1[fm][kk], bfr[kk], acc[1][fm]);
        __builtin_amdgcn_s_setprio(0);
        if (t < nt - 1) asm volatile("s_waitcnt vmcnt(2)" ::: "memory");
        asm volatile("s_barrier" ::: "memory");
    }
#undef SGA
#undef SGB

    // epilogue: bias + f32 store
    float bv = bias[n0 + wc * 16 + l15];
#pragma unroll
    for (int mh = 0; mh < 2; ++mh)
#pragma unroll
        for (int fm = 0; fm < 4; ++fm)
#pragma unroll
            for (int j = 0; j < 4; ++j) {
                size_t row = (size_t)(m0 + wr * 128 + mh * 64 + fm * 16 + l4 * 4 + j);
                int col = n0 + wc * 16 + l15;
                Cp[row * (size_t)N + col] = acc[mh][fm][j] + bv;
            }
}

// ---------- flash attention: 8 waves, KV-split x2, fixed-max softmax.
// Row-sum via VALU tree; anti-phase KV tile rotation; single barrier/tile;
// conflict-free transposed merge. 64 KiB LDS, 2 blocks/CU.
// (Proven bit-stable across R9-R11: absmax 0.001342773.) ----------
__global__ __launch_bounds__(512, 4) void attn_kernel(const u16* __restrict__ qkv,
                                                      const u16* __restrict__ Vt,
                                                      u16* __restrict__ vals) {
    __shared__ __align__(16) char lds[65536];
    const int L = blockIdx.x;            // 512 blocks, 1-D
    const int ord = L >> 3;
    const int hb = (L & 7) * 4 + (ord >> 4);
    const int qt = ord & 15;
    const int h = hb & 15, b = hb >> 4;
    const int st8 = (ord & 1) << 3;      // anti-phase: odd blocks start at tile 8
    const int tid = threadIdx.x, lane = tid & 63, wave = tid >> 6;
    const int gtid = tid & 255, qsub = wave & 3, kvh = wave >> 2;
    const int l31 = lane & 31, hi = lane >> 5;
    const float S2E = 0.18033688f;   // 0.125 * log2(e)

    // Q B-fragments, pre-scaled by S2E (re-rounded to bf16)
    const u16* qbase = qkv + (size_t)(b * 2048 + qt * 128 + qsub * 32 + l31) * 3072 + h * 192;
    bf16x8 Qf[4];
#pragma unroll
    for (int ks = 0; ks < 4; ++ks) {
        bf16x8 q = *(const bf16x8*)(qbase + ks * 16 + hi * 8);
#pragma unroll
        for (int j = 0; j < 8; ++j) {
            float f = __uint_as_float(((unsigned)(u16)q[j]) << 16) * S2E;
            q[j] = (short)f2bf(f);
        }
        Qf[ks] = q;
    }

    // staging: chunk c = i*256 + gtid -> (fi=c>>6, dl=c&63); fragment-ordered source
    const u16* kpb[2];
    const u16* vpb[2];
    int dst[2];
#pragma unroll
    for (int i = 0; i < 2; ++i) {
        int c = i * 256 + gtid;
        int fi = c >> 6, dl = c & 63;
        int mm = fi >> 2, ks = fi & 3;
        int row = mm * 32 + (dl & 31);
        int col = ks * 16 + (dl >> 5) * 8;
        kpb[i] = qkv + (size_t)(b * 2048 + kvh * 1024 + row) * 3072 + h * 192 + 64 + col;
        vpb[i] = Vt + ((size_t)((b * 16 + h) * 64 + row)) * 2048 + kvh * 1024 + col;
        dst[i] = fi * 512;
    }
    u16* Kst = (u16*)lds + kvh * 8192;          // 2 bufs x 4096 u16
    u16* Vst = (u16*)lds + 16384 + kvh * 8192;

    f32x16 accO[2];
#pragma unroll
    for (int md = 0; md < 2; ++md)
#pragma unroll
        for (int r = 0; r < 16; ++r) accO[md][r] = 0.f;
    float accLs = 0.f;

    const char* KsL = (const char*)Kst + lane * 16;
    const char* VsL = (const char*)Vst + lane * 16;

    // prologue: stage tile st8 into buf 0
#pragma unroll
    for (int i = 0; i < 2; ++i) gload16(kpb[i] + (size_t)st8 * 196608, Kst + dst[i]);
#pragma unroll
    for (int i = 0; i < 2; ++i) gload16(vpb[i] + (size_t)st8 * 64, Vst + dst[i]);

    for (int t = 0; t < 16; ++t) {
        asm volatile("s_waitcnt vmcnt(0)" ::: "memory");
        asm volatile("s_barrier" ::: "memory");

        if (t < 15) {
            int phys = (t + 1 + st8) & 15;
            u16* kd = Kst + ((t + 1) & 1) * 4096;
            u16* vd = Vst + ((t + 1) & 1) * 4096;
#pragma unroll
            for (int i = 0; i < 2; ++i) gload16(kpb[i] + (size_t)phys * 196608, kd + dst[i]);
#pragma unroll
            for (int i = 0; i < 2; ++i) gload16(vpb[i] + (size_t)phys * 64, vd + dst[i]);
        }

        const char* Kb = KsL + (t & 1) * 8192;
        const char* Vb = VsL + (t & 1) * 8192;

        // ---- QK^T (S^T): sc[m] rows = sk, cols = q (lane&31)
        f32x16 sc[2];
        __builtin_amdgcn_s_setprio(1);
#pragma unroll
        for (int m = 0; m < 2; ++m) {
            f32x16 c;
#pragma unroll
            for (int r = 0; r < 16; ++r) c[r] = 0.f;
#pragma unroll
            for (int ks = 0; ks < 4; ++ks) {
                bf16x8 kf = *(const bf16x8*)(Kb + (m * 4 + ks) * 1024);
                c = mfma32(kf, Qf[ks], c);
            }
            sc[m] = c;
        }
        __builtin_amdgcn_s_setprio(0);

        bf16x8 Pf[4];
#pragma unroll
        for (int r = 0; r < 16; ++r)
            sc[0][r] = __builtin_amdgcn_exp2f(sc[0][r]);
        {
            float q0 = (sc[0][0] + sc[0][1]) + (sc[0][2] + sc[0][3]);
            float q1 = (sc[0][4] + sc[0][5]) + (sc[0][6] + sc[0][7]);
            float q2 = (sc[0][8] + sc[0][9]) + (sc[0][10] + sc[0][11]);
            float q3 = (sc[0][12] + sc[0][13]) + (sc[0][14] + sc[0][15]);
            accLs += (q0 + q1) + (q2 + q3);
        }
        {
            unsigned W0[4], W1[4];
#pragma unroll
            for (int g = 0; g < 4; ++g) {
                asm("v_cvt_pk_bf16_f32 %0, %1, %2"
                    : "=v"(W0[g]) : "v"(sc[0][4 * g + 0]), "v"(sc[0][4 * g + 1]));
                asm("v_cvt_pk_bf16_f32 %0, %1, %2"
                    : "=v"(W1[g]) : "v"(sc[0][4 * g + 2]), "v"(sc[0][4 * g + 3]));
            }
#pragma unroll
            for (int kpair = 0; kpair < 2; ++kpair) {
                unsigned xa = W0[2 * kpair], ya = W0[2 * kpair + 1];
                unsigned xb = W1[2 * kpair], yb = W1[2 * kpair + 1];
                asm volatile("v_permlane32_swap_b32 %0, %1" : "+v"(xa), "+v"(ya));
                asm volatile("v_permlane32_swap_b32 %0, %1" : "+v"(xb), "+v"(yb));
                union { unsigned w[4]; bf16x8 v; } u;
                u.w[0] = xa; u.w[1] = xb; u.w[2] = ya; u.w[3] = yb;
                Pf[kpair] = u.v;
            }
        }

        // ---- PV half A (ks=0,1)
        __builtin_amdgcn_s_setprio(1);
#pragma unroll
        for (int md = 0; md < 2; ++md) {
            f32x16 c = accO[md];
#pragma unroll
            for (int ks = 0; ks < 2; ++ks) {
                bf16x8 vf = *(const bf16x8*)(Vb + (md * 4 + ks) * 1024);
                c = mfma32(vf, Pf[ks], c);
            }
            accO[md] = c;
        }
        __builtin_amdgcn_s_setprio(0);

#pragma unroll
        for (int r = 0; r < 16; ++r)
            sc[1][r] = __builtin_amdgcn_exp2f(sc[1][r]);
        {
            float q0 = (sc[1][0] + sc[1][1]) + (sc[1][2] + sc[1][3]);
            float q1 = (sc[1][4] + sc[1][5]) + (sc[1][6] + sc[1][7]);
            float q2 = (sc[1][8] + sc[1][9]) + (sc[1][10] + sc[1][11]);
            float q3 = (sc[1][12] + sc[1][13]) + (sc[1][14] + sc[1][15]);
            accLs += (q0 + q1) + (q2 + q3);
        }
        {
            unsigned W0[4], W1[4];
#pragma unroll
            for (int g = 0; g < 4; ++g) {
                asm("v_cvt_pk_bf16_f32 %0, %1, %2"
                    : "=v"(W0[g]) : "v"(sc[1][4 * g + 0]), "v"(sc[1][4 * g + 1]));
                asm("v_cvt_pk_bf16_f32 %0, %1, %2"
                    : "=v"(W1[g]) : "v"(sc[1][4 * g + 2]), "v"(sc[1][4 * g + 3]));
            }
#pragma unroll
            for (int kpair = 0; kpair < 2; ++kpair) {
                unsigned xa = W0[2 * kpair], ya = W0[2 * kpair + 1];
                unsigned xb = W1[2 * kpair], yb = W1[2 * kpair + 1];
                asm volatile("v_permlane32_swap_b32 %0, %1" : "+v"(xa), "+v"(ya));
                asm volatile("v_permlane32_swap_b32 %0, %1" : "+v"(xb), "+v"(yb));
                union { unsigned w[4]; bf16x8 v; } u;
                u.w[0] = xa; u.w[1] = xb; u.w[2] = ya; u.w[3] = yb;
                Pf[2 + kpair] = u.v;
            }
        }

        // ---- PV half B (ks=2,3)
        __builtin_amdgcn_s_setprio(1);
#pragma unroll
        for (int md = 0; md < 2; ++md) {
            f32x16 c = accO[md];
#pragma unroll
            for (int ks = 2; ks < 4; ++ks) {
                bf16x8 vf = *(const bf16x8*)(Vb + (md * 4 + ks) * 1024);
                c = mfma32(vf, Pf[ks], c);
            }
            accO[md] = c;
        }
        __builtin_amdgcn_s_setprio(0);
    }

    float lt;
    {
        float xa = accLs, xb = accLs;
        asm volatile("v_permlane32_swap_b32 %0, %1" : "+v"(xa), "+v"(xb));
        lt = xa + xb;
    }

    // ---- merge the two KV halves via LDS (transposed, conflict-free)
    float* MO = (float*)lds;
    float* ML = (float*)(lds + 32768);
    __syncthreads();
    if (kvh == 1) {
        int r = qsub * 64 + lane;
#pragma unroll
        for (int md = 0; md < 2; ++md)
#pragma unroll
            for (int g = 0; g < 4; ++g)
#pragma unroll
                for (int j = 0; j < 4; ++j)
                    MO[(md * 16 + 4 * g + j) * 256 + r] = accO[md][4 * g + j];
        ML[r] = lt;
    }
    __syncthreads();
    if (kvh == 0) {
        int r = qsub * 64 + lane;
        float inv = 1.f / (lt + ML[r]);
        size_t rowoff = (size_t)(b * 2048 + qt * 128 + qsub * 32 + l31) * 1024 + h * 64;
#pragma unroll
        for (int md = 0; md < 2; ++md)
#pragma unroll
            for (int g = 0; g < 4; ++g) {
                float w0 = MO[(md * 16 + 4 * g + 0) * 256 + r];
                float w1 = MO[(md * 16 + 4 * g + 1) * 256 + r];
                float w2 = MO[(md * 16 + 4 * g + 2) * 256 + r];
                float w3 = MO[(md * 16 + 4 * g + 3) * 256 + r];
                u16x4 o = { f2bf((accO[md][4 * g + 0] + w0) * inv),
                            f2bf((accO[md][4 * g + 1] + w1) * inv),
                            f2bf((accO[md][4 * g + 2] + w2) * inv),
                            f2bf((accO[md][4 * g + 3] + w3) * inv) };
                *(u16x4*)(vals + rowoff + md * 32 + 8 * g + 4 * hi) = o;
            }
    }
}

// ---------- launch ----------
extern "C" void kernel_launch(void* const* d_in, const int* in_sizes, int n_in,
                              void* d_out, int out_size, void* d_ws, size_t ws_size,
                              hipStream_t stream) {
    const float* x    = (const float*)d_in[0];
    const float* Wqkv = (const float*)d_in[1];
    const float* bqkv = (const float*)d_in[2];
    const float* Wo   = (const float*)d_in[3];
    const float* bo   = (const float*)d_in[4];
    float* out = (float*)d_out;

    char* ws = (char*)d_ws;
    u16* x_bf    = (u16*)(ws);                   // 8,388,608 B
    u16* Wqkv_bf = (u16*)(ws + 8388608);         // 6,291,456 B (contiguous with x_bf)
    u16* Wo_bf   = (u16*)(ws + 14680064);        // 2,097,152 B (contiguous)
    u16* qkv_bf  = (u16*)(ws + 16777216);
    u16* Vt      = (u16*)(ws + 41943040);
    u16* vals    = (u16*)(ws + 50331648);

    cvt_all<<<8192, 256, 0, stream>>>(x, Wqkv, Wo, x_bf);

    // qkv = x @ Wqkv^T + bqkv  (+ fused V^T extraction)  (M=4096, N=3072, K=1024)
    gemm192<<<dim3(16, 16), 512, 0, stream>>>(x_bf, Wqkv_bf, bqkv, qkv_bf, Vt,
                                              4096, 3072, 1024);

    attn_kernel<<<512, 512, 0, stream>>>(qkv_bf, Vt, vals);

    // out = vals @ Wo^T + bo  (M=4096, N=1024, K=1024), 256x64 tile, grid 256
    gemm_out<<<dim3(16, 16), 512, 0, stream>>>(vals, Wo_bf, bo, out,
                                               4096, 1024, 1024);
}